// Round 8
// baseline (435.899 us; speedup 1.0000x reference)
//
#include <hip/hip_runtime.h>
#include <hip/hip_bf16.h>
#include <math.h>

#define N_NODES 50000
#define N_EDGES 800000
#define DIMS 5
#define IN_C 32
#define OUT_C 32
#define FEAT 160            // DIMS*OUT_C
#define ATT_LD 65           // 2*OUT_C+1
#define NEG_SLOPE 0.2f
#define BSHIFT 7
#define BROWS 128           // rows per bucket
#define NBUCK ((N_NODES + BROWS - 1) / BROWS)   // 391
#define CAP 3072            // max edges per bucket (mean 2048, +22 sigma)

// ---- zero bucket counters ----
__global__ void zero_kernel(int* bcnt) {
    int i = blockIdx.x * blockDim.x + threadIdx.x;
    if (i < NBUCK) bcnt[i] = 0;
}

// ---- pass 1: bin edges by row>>7; also emit fedge (edge_index as float) ----
__global__ void bin_kernel(const int* __restrict__ ei, float* __restrict__ fedge,
                           int* __restrict__ bcnt, int2* __restrict__ staged) {
    int e = blockIdx.x * blockDim.x + threadIdx.x;
    if (e >= N_EDGES) return;
    int r = ei[e];
    int c = ei[N_EDGES + e];
    __builtin_nontemporal_store((float)r, &fedge[e]);
    __builtin_nontemporal_store((float)c, &fedge[N_EDGES + e]);
    int b = r >> BSHIFT;
    int pos = atomicAdd(&bcnt[b], 1);
    staged[(size_t)b * CAP + pos] = make_int2(c, (e << BSHIFT) | (r & (BROWS - 1)));
}

// ---- exclusive scan over 391 bucket counts (1 block) ----
__global__ void bscan_kernel(const int* __restrict__ bcnt, int* __restrict__ boff) {
    __shared__ int buf[512];
    int t = threadIdx.x;
    int v = (t < NBUCK) ? bcnt[t] : 0;
    buf[t] = v;
    __syncthreads();
    for (int off = 1; off < 512; off <<= 1) {
        int add = (t >= off) ? buf[t - off] : 0;
        __syncthreads();
        buf[t] += add;
        __syncthreads();
    }
    if (t < NBUCK) boff[t] = buf[t] - v;
}

// ---- pass 2: per-bucket CSR build in LDS; writes rowStart + csr (contiguous region) ----
__global__ __launch_bounds__(256) void build_kernel(
        const int2* __restrict__ staged, const int* __restrict__ bcnt,
        const int* __restrict__ boff,
        int2* __restrict__ csr, int* __restrict__ rowStart) {
    __shared__ int2 sst[CAP];
    __shared__ int rcount[BROWS];
    __shared__ int rexcl[BROWS];
    __shared__ int sbuf[BROWS];
    int b = blockIdx.x;
    int t = threadIdx.x;
    int cnt  = bcnt[b];
    int base = boff[b];
    const int2* sg = staged + (size_t)b * CAP;
    for (int i = t; i < cnt; i += 256) sst[i] = sg[i];
    if (t < BROWS) rcount[t] = 0;
    __syncthreads();
    for (int i = t; i < cnt; i += 256) atomicAdd(&rcount[sst[i].y & (BROWS - 1)], 1);
    __syncthreads();
    if (t < BROWS) sbuf[t] = rcount[t];
    __syncthreads();
    for (int off = 1; off < BROWS; off <<= 1) {
        int add = (t < BROWS && t >= off) ? sbuf[t - off] : 0;
        __syncthreads();
        if (t < BROWS) sbuf[t] += add;
        __syncthreads();
    }
    if (t < BROWS) {
        rexcl[t] = sbuf[t] - rcount[t];
        int idx = b * BROWS + t;
        if (idx <= N_NODES) rowStart[idx] = base + rexcl[t];
        rcount[t] = 0;                 // reuse as per-row cursor
    }
    __syncthreads();
    for (int i = t; i < cnt; i += 256) {
        int2 p = sst[i];
        int rl = p.y & (BROWS - 1);
        int lp = atomicAdd(&rcount[rl], 1);
        csr[base + rexcl[rl] + lp] = make_int2(p.x, p.y >> BSHIFT);
    }
}

// ---- fused h (bf16) + ai/aj. thread = (n, og) ----
__global__ __launch_bounds__(256) void hfused_kernel(
        const float* __restrict__ x, const float* __restrict__ W,
        const float* __restrict__ att,
        __hip_bfloat16* __restrict__ h2,
        float* __restrict__ ai, float* __restrict__ aj) {
    int idx = blockIdx.x * 256 + threadIdx.x;
    if (idx >= N_NODES * 8) return;
    int n = idx >> 3;
    int og = idx & 7;
    const float4* xr4 = (const float4*)(x + (size_t)n * FEAT);

    float acc[DIMS][4];
#pragma unroll
    for (int d = 0; d < DIMS; ++d)
#pragma unroll
        for (int q = 0; q < 4; ++q) acc[d][q] = 0.f;

#pragma unroll
    for (int ib = 0; ib < 8; ++ib) {
        float xs[20];
#pragma unroll
        for (int q = 0; q < 5; ++q) {
            float4 v = xr4[ib * 5 + q];
            xs[q * 4 + 0] = v.x; xs[q * 4 + 1] = v.y;
            xs[q * 4 + 2] = v.z; xs[q * 4 + 3] = v.w;
        }
#pragma unroll
        for (int ii = 0; ii < 4; ++ii) {
            int i = ib * 4 + ii;
#pragma unroll
            for (int d = 0; d < DIMS; ++d) {
                float xv = xs[ii * 5 + d];
                float4 wv = *(const float4*)(W + ((d * IN_C + i) * OUT_C) + og * 4);
                acc[d][0] += xv * wv.x; acc[d][1] += xv * wv.y;
                acc[d][2] += xv * wv.z; acc[d][3] += xv * wv.w;
            }
        }
    }

    __hip_bfloat16* hp = h2 + (size_t)n * FEAT + og * 4;
#pragma unroll
    for (int d = 0; d < DIMS; ++d) {
        union { __hip_bfloat16 h[4]; uint2 u; } pk;
        pk.h[0] = __float2bfloat16(acc[d][0]);
        pk.h[1] = __float2bfloat16(acc[d][1]);
        pk.h[2] = __float2bfloat16(acc[d][2]);
        pk.h[3] = __float2bfloat16(acc[d][3]);
        *(uint2*)(hp + d * OUT_C) = pk.u;
    }

    float pa[DIMS], pb[DIMS];
#pragma unroll
    for (int d = 0; d < DIMS; ++d) {
        const float* at = att + d * ATT_LD + og * 4;
        const float* bt = at + OUT_C;
        pa[d] = acc[d][0] * at[0] + acc[d][1] * at[1] + acc[d][2] * at[2] + acc[d][3] * at[3];
        pb[d] = acc[d][0] * bt[0] + acc[d][1] * bt[1] + acc[d][2] * bt[2] + acc[d][3] * bt[3];
    }
#pragma unroll
    for (int m = 1; m < 8; m <<= 1) {
#pragma unroll
        for (int d = 0; d < DIMS; ++d) {
            pa[d] += __shfl_xor(pa[d], m, 8);
            pb[d] += __shfl_xor(pb[d], m, 8);
        }
    }
    if (og == 0) {
#pragma unroll
        for (int d = 0; d < DIMS; ++d) {
            ai[n * DIMS + d] = pa[d];
            aj[n * DIMS + d] = pb[d];
        }
    }
}

// ---- es (coalesced, edge order) -> alpha_buf region ----
__global__ void es_kernel(const int* __restrict__ ei,
                          const float* __restrict__ edge_attr,
                          const float* __restrict__ ai, const float* __restrict__ aj,
                          const float* __restrict__ att,
                          float* __restrict__ es_edge) {
    int idx = blockIdx.x * blockDim.x + threadIdx.x;
    if (idx >= N_EDGES * DIMS) return;
    int e = idx / DIMS;
    int d = idx - e * DIMS;
    int r = ei[e];
    int c = ei[N_EDGES + e];
    float s = ai[r * DIMS + d] + aj[c * DIMS + d]
            + edge_attr[idx] * att[d * ATT_LD + 2 * OUT_C];
    s = (s > 0.f) ? s : NEG_SLOPE * s;
    es_edge[idx] = __expf(s);
}

// ---- out: 320-thread blocks, 8 nodes/block in 40-lane groups ----
__global__ __launch_bounds__(320) void out_kernel(
        const __hip_bfloat16* __restrict__ h2,
        const float* __restrict__ es_edge,
        const int2* __restrict__ csr,
        const int* __restrict__ rowStart,
        float* __restrict__ out, float* __restrict__ ssum) {
    int g = threadIdx.x / 40;          // node group 0..7
    int l = threadIdx.x - g * 40;      // 0..39
    int node = blockIdx.x * 8 + g;
    int d = l >> 3;                    // 8 lanes per d
    int start = rowStart[node];
    int end   = rowStart[node + 1];
    float a0 = 0.f, a1 = 0.f, a2 = 0.f, a3 = 0.f, ss = 0.f;
    int k = start;
    for (; k + 3 < end; k += 4) {
        int2 ce[4]; float av[4]; uint2 hv[4];
#pragma unroll
        for (int u = 0; u < 4; ++u) ce[u] = csr[k + u];
#pragma unroll
        for (int u = 0; u < 4; ++u) av[u] = es_edge[(size_t)ce[u].y * DIMS + d];
#pragma unroll
        for (int u = 0; u < 4; ++u)
            hv[u] = *(const uint2*)(h2 + (size_t)ce[u].x * FEAT + l * 4);
#pragma unroll
        for (int u = 0; u < 4; ++u) {
            float a = av[u];
            ss += a;
            a0 += a * __uint_as_float(hv[u].x << 16);
            a1 += a * __uint_as_float(hv[u].x & 0xffff0000u);
            a2 += a * __uint_as_float(hv[u].y << 16);
            a3 += a * __uint_as_float(hv[u].y & 0xffff0000u);
        }
    }
    for (; k < end; ++k) {
        int2 ce = csr[k];
        float a = es_edge[(size_t)ce.y * DIMS + d];
        uint2 hv = *(const uint2*)(h2 + (size_t)ce.x * FEAT + l * 4);
        ss += a;
        a0 += a * __uint_as_float(hv.x << 16);
        a1 += a * __uint_as_float(hv.x & 0xffff0000u);
        a2 += a * __uint_as_float(hv.y << 16);
        a3 += a * __uint_as_float(hv.y & 0xffff0000u);
    }
    float inv = 1.f / (ss + 1e-16f);
    union { float f[4]; unsigned long long u[2]; } o;
    o.f[0] = a0 * inv; o.f[1] = a1 * inv; o.f[2] = a2 * inv; o.f[3] = a3 * inv;
    unsigned long long* op = (unsigned long long*)(out + (size_t)node * FEAT + l * 4);
    __builtin_nontemporal_store(o.u[0], op);
    __builtin_nontemporal_store(o.u[1], op + 1);
    if ((l & 7) == 0) ssum[node * DIMS + d] = ss;
}

// ---- alpha: in-place divide of precomputed es by ssum[row] ----
__global__ void alpha_kernel(const int* __restrict__ ei, float* __restrict__ alpha_buf,
                             const float* __restrict__ ssum) {
    int idx = blockIdx.x * blockDim.x + threadIdx.x;
    if (idx >= N_EDGES * DIMS) return;
    int e = idx / DIMS;
    int d = idx - e * DIMS;
    int r = ei[e];
    alpha_buf[idx] = alpha_buf[idx] / (ssum[r * DIMS + d] + 1e-16f);
}

extern "C" void kernel_launch(void* const* d_in, const int* in_sizes, int n_in,
                              void* d_out, int out_size, void* d_ws, size_t ws_size,
                              hipStream_t stream) {
    const float* x         = (const float*)d_in[0];
    const int*   ei        = (const int*)d_in[1];
    const float* edge_attr = (const float*)d_in[2];
    const float* W         = (const float*)d_in[3];
    const float* att       = (const float*)d_in[4];

    float* out_buf   = (float*)d_out;                       // 8,000,000 f32
    float* alpha_buf = out_buf + (size_t)N_NODES * FEAT;    // 4,000,000 f32 (es first, then alpha)
    float* fedge     = alpha_buf + (size_t)N_EDGES * DIMS;  // 1,600,000 f32

    char* wsb = (char*)d_ws;
    __hip_bfloat16* h2 = (__hip_bfloat16*)wsb;              // 16,000,000 B
    float* ai     = (float*)(wsb + 16000000);               // 1,000,000 B
    float* aj     = (float*)(wsb + 17000000);               // 1,000,000 B
    float* ssum   = (float*)(wsb + 18000000);               // 1,000,000 B
    int2* csr     = (int2*)(wsb + 19000000);                // 6,400,000 B
    int2* staged  = (int2*)(wsb + 25400000);                // 391*3072*8 = 9,609,216 B
    int* bcnt     = (int*)(wsb + 35009216);                 // 1,564 B
    int* boff     = (int*)(wsb + 35010780);                 // 1,564 B
    int* rowStart = (int*)(wsb + 35012344);                 // 200,004 B

    const int B = 256;

    zero_kernel<<<(NBUCK + B - 1) / B, B, 0, stream>>>(bcnt);
    bin_kernel<<<(N_EDGES + B - 1) / B, B, 0, stream>>>(ei, fedge, bcnt, staged);
    bscan_kernel<<<1, 512, 0, stream>>>(bcnt, boff);
    build_kernel<<<NBUCK, 256, 0, stream>>>(staged, bcnt, boff, csr, rowStart);
    hfused_kernel<<<(N_NODES * 8 + B - 1) / B, B, 0, stream>>>(x, W, att, h2, ai, aj);
    es_kernel<<<(N_EDGES * DIMS + B - 1) / B, B, 0, stream>>>(ei, edge_attr, ai, aj, att,
                                                              alpha_buf);
    out_kernel<<<N_NODES / 8, 320, 0, stream>>>(h2, alpha_buf, csr, rowStart, out_buf, ssum);
    alpha_kernel<<<(N_EDGES * DIMS + B - 1) / B, B, 0, stream>>>(ei, alpha_buf, ssum);
}

// Round 9
// 170.178 us; speedup vs baseline: 2.5614x; 2.5614x over previous
//
#include <hip/hip_runtime.h>
#include <hip/hip_bf16.h>
#include <math.h>

#define N_NODES 50000
#define N_EDGES 800000
#define DIMS 5
#define IN_C 32
#define OUT_C 32
#define FEAT 160            // DIMS*OUT_C
#define ATT_LD 65           // 2*OUT_C+1
#define NEG_SLOPE 0.2f
#define BSHIFT 7
#define BROWS 128                                   // rows per bucket
#define NBUCK ((N_NODES + BROWS - 1) / BROWS)       // 391
#define CAP 2560                                    // max edges/bucket (mean 2048, +11 sigma)
#define K1_EPB 4096
#define K1_BLOCKS ((N_EDGES + K1_EPB - 1) / K1_EPB) // 196

// ---- K1: per-block LDS histogram + per-edge local rank; fedge conversion ----
__global__ __launch_bounds__(1024) void hist_kernel(
        const int* __restrict__ ei, float* __restrict__ fedge,
        int* __restrict__ ghist, unsigned short* __restrict__ lofs) {
    __shared__ int hist[NBUCK];
    int blk = blockIdx.x, t = threadIdx.x;
    if (t < NBUCK) hist[t] = 0;
    __syncthreads();
#pragma unroll
    for (int u = 0; u < 4; ++u) {
        int e = blk * K1_EPB + u * 1024 + t;
        if (e < N_EDGES) {
            int r = ei[e];
            int c = ei[N_EDGES + e];
            __builtin_nontemporal_store((float)r, &fedge[e]);
            __builtin_nontemporal_store((float)c, &fedge[N_EDGES + e]);
            int b = r >> BSHIFT;
            int lo = atomicAdd(&hist[b], 1);
            lofs[e] = (unsigned short)lo;
        }
    }
    __syncthreads();
    if (t < NBUCK) ghist[blk * NBUCK + t] = hist[t];
}

// ---- K2a: column sums -> btot[b] ----
__global__ void colsum_kernel(const int* __restrict__ ghist, int* __restrict__ btot) {
    __shared__ int red[256];
    int b = blockIdx.x, t = threadIdx.x;
    int s = 0;
    for (int blk = t; blk < K1_BLOCKS; blk += 256) s += ghist[blk * NBUCK + b];
    red[t] = s;
    __syncthreads();
    for (int off = 128; off > 0; off >>= 1) {
        if (t < off) red[t] += red[t + off];
        __syncthreads();
    }
    if (t == 0) btot[b] = red[0];
}

// ---- K2b: exclusive scan of btot -> bbase ----
__global__ void bscan2_kernel(const int* __restrict__ btot, int* __restrict__ bbase) {
    __shared__ int buf[512];
    int t = threadIdx.x;
    int v = (t < NBUCK) ? btot[t] : 0;
    buf[t] = v;
    __syncthreads();
    for (int off = 1; off < 512; off <<= 1) {
        int add = (t >= off) ? buf[t - off] : 0;
        __syncthreads();
        buf[t] += add;
        __syncthreads();
    }
    if (t < NBUCK) bbase[t] = buf[t] - v;
}

// ---- K2c: per-bucket exclusive scan over blocks -> base2[blk][b] ----
__global__ void colscan_kernel(const int* __restrict__ ghist, const int* __restrict__ bbase,
                               int* __restrict__ base2) {
    __shared__ int buf[256];
    int b = blockIdx.x, t = threadIdx.x;
    int v = (t < K1_BLOCKS) ? ghist[t * NBUCK + b] : 0;
    buf[t] = v;
    __syncthreads();
    for (int off = 1; off < 256; off <<= 1) {
        int add = (t >= off) ? buf[t - off] : 0;
        __syncthreads();
        buf[t] += add;
        __syncthreads();
    }
    if (t < K1_BLOCKS) base2[t * NBUCK + b] = bbase[b] + buf[t] - v;
}

// ---- K3: place edges into bucket-sorted staged[] (no atomics, block-local runs) ----
__global__ __launch_bounds__(1024) void place_kernel(
        const int* __restrict__ ei, const unsigned short* __restrict__ lofs,
        const int* __restrict__ base2, int2* __restrict__ staged) {
    __shared__ int lbase[NBUCK];
    int blk = blockIdx.x, t = threadIdx.x;
    if (t < NBUCK) lbase[t] = base2[blk * NBUCK + t];
    __syncthreads();
#pragma unroll
    for (int u = 0; u < 4; ++u) {
        int e = blk * K1_EPB + u * 1024 + t;
        if (e < N_EDGES) {
            int r = ei[e];
            int c = ei[N_EDGES + e];
            int b = r >> BSHIFT;
            int pos = lbase[b] + (int)lofs[e];
            staged[pos] = make_int2(c, (e << BSHIFT) | (r & (BROWS - 1)));
        }
    }
}

// ---- build: per-bucket CSR in LDS -> rowStart + csr ----
__global__ __launch_bounds__(256) void build_kernel(
        const int2* __restrict__ staged, const int* __restrict__ btot,
        const int* __restrict__ bbase,
        int2* __restrict__ csr, int* __restrict__ rowStart) {
    __shared__ int2 sst[CAP];
    __shared__ int rcount[BROWS];
    __shared__ int rexcl[BROWS];
    __shared__ int sbuf[BROWS];
    int b = blockIdx.x;
    int t = threadIdx.x;
    int cnt  = btot[b];
    int base = bbase[b];
    const int2* sg = staged + base;
    for (int i = t; i < cnt; i += 256) sst[i] = sg[i];
    if (t < BROWS) rcount[t] = 0;
    __syncthreads();
    for (int i = t; i < cnt; i += 256) atomicAdd(&rcount[sst[i].y & (BROWS - 1)], 1);
    __syncthreads();
    if (t < BROWS) sbuf[t] = rcount[t];
    __syncthreads();
    for (int off = 1; off < BROWS; off <<= 1) {
        int add = (t < BROWS && t >= off) ? sbuf[t - off] : 0;
        __syncthreads();
        if (t < BROWS) sbuf[t] += add;
        __syncthreads();
    }
    if (t < BROWS) {
        rexcl[t] = sbuf[t] - rcount[t];
        int idx = b * BROWS + t;
        if (idx <= N_NODES) rowStart[idx] = base + rexcl[t];
        rcount[t] = 0;                 // reuse as per-row cursor
    }
    __syncthreads();
    for (int i = t; i < cnt; i += 256) {
        int2 p = sst[i];
        int rl = p.y & (BROWS - 1);
        int lp = atomicAdd(&rcount[rl], 1);
        csr[base + rexcl[rl] + lp] = make_int2(p.x, p.y >> BSHIFT);
    }
}

// ---- fused h (bf16) + ai/aj. thread = (n, og) ----
__global__ __launch_bounds__(256) void hfused_kernel(
        const float* __restrict__ x, const float* __restrict__ W,
        const float* __restrict__ att,
        __hip_bfloat16* __restrict__ h2,
        float* __restrict__ ai, float* __restrict__ aj) {
    int idx = blockIdx.x * 256 + threadIdx.x;
    if (idx >= N_NODES * 8) return;
    int n = idx >> 3;
    int og = idx & 7;
    const float4* xr4 = (const float4*)(x + (size_t)n * FEAT);

    float acc[DIMS][4];
#pragma unroll
    for (int d = 0; d < DIMS; ++d)
#pragma unroll
        for (int q = 0; q < 4; ++q) acc[d][q] = 0.f;

#pragma unroll
    for (int ib = 0; ib < 8; ++ib) {
        float xs[20];
#pragma unroll
        for (int q = 0; q < 5; ++q) {
            float4 v = xr4[ib * 5 + q];
            xs[q * 4 + 0] = v.x; xs[q * 4 + 1] = v.y;
            xs[q * 4 + 2] = v.z; xs[q * 4 + 3] = v.w;
        }
#pragma unroll
        for (int ii = 0; ii < 4; ++ii) {
            int i = ib * 4 + ii;
#pragma unroll
            for (int d = 0; d < DIMS; ++d) {
                float xv = xs[ii * 5 + d];
                float4 wv = *(const float4*)(W + ((d * IN_C + i) * OUT_C) + og * 4);
                acc[d][0] += xv * wv.x; acc[d][1] += xv * wv.y;
                acc[d][2] += xv * wv.z; acc[d][3] += xv * wv.w;
            }
        }
    }

    __hip_bfloat16* hp = h2 + (size_t)n * FEAT + og * 4;
#pragma unroll
    for (int d = 0; d < DIMS; ++d) {
        union { __hip_bfloat16 h[4]; uint2 u; } pk;
        pk.h[0] = __float2bfloat16(acc[d][0]);
        pk.h[1] = __float2bfloat16(acc[d][1]);
        pk.h[2] = __float2bfloat16(acc[d][2]);
        pk.h[3] = __float2bfloat16(acc[d][3]);
        *(uint2*)(hp + d * OUT_C) = pk.u;
    }

    float pa[DIMS], pb[DIMS];
#pragma unroll
    for (int d = 0; d < DIMS; ++d) {
        const float* at = att + d * ATT_LD + og * 4;
        const float* bt = at + OUT_C;
        pa[d] = acc[d][0] * at[0] + acc[d][1] * at[1] + acc[d][2] * at[2] + acc[d][3] * at[3];
        pb[d] = acc[d][0] * bt[0] + acc[d][1] * bt[1] + acc[d][2] * bt[2] + acc[d][3] * bt[3];
    }
#pragma unroll
    for (int m = 1; m < 8; m <<= 1) {
#pragma unroll
        for (int d = 0; d < DIMS; ++d) {
            pa[d] += __shfl_xor(pa[d], m, 8);
            pb[d] += __shfl_xor(pb[d], m, 8);
        }
    }
    if (og == 0) {
#pragma unroll
        for (int d = 0; d < DIMS; ++d) {
            ai[n * DIMS + d] = pa[d];
            aj[n * DIMS + d] = pb[d];
        }
    }
}

// ---- es (coalesced, edge order, bf16) ----
__global__ void es_kernel(const int* __restrict__ ei,
                          const float* __restrict__ edge_attr,
                          const float* __restrict__ ai, const float* __restrict__ aj,
                          const float* __restrict__ att,
                          unsigned short* __restrict__ es2) {
    int idx = blockIdx.x * blockDim.x + threadIdx.x;
    if (idx >= N_EDGES * DIMS) return;
    int e = idx / DIMS;
    int d = idx - e * DIMS;
    int r = ei[e];
    int c = ei[N_EDGES + e];
    float s = ai[r * DIMS + d] + aj[c * DIMS + d]
            + edge_attr[idx] * att[d * ATT_LD + 2 * OUT_C];
    s = (s > 0.f) ? s : NEG_SLOPE * s;
    __hip_bfloat16 h = __float2bfloat16(__expf(s));
    es2[idx] = *(unsigned short*)&h;
}

__device__ inline float bf2f(unsigned short u) {
    return __uint_as_float(((unsigned)u) << 16);
}

// ---- out: 320-thread blocks, 8 nodes/block in 40-lane groups; unroll 8 ----
__global__ __launch_bounds__(320) void out_kernel(
        const __hip_bfloat16* __restrict__ h2,
        const unsigned short* __restrict__ es2,
        const int2* __restrict__ csr,
        const int* __restrict__ rowStart,
        float* __restrict__ out, float* __restrict__ ssum) {
    int g = threadIdx.x / 40;          // node group 0..7
    int l = threadIdx.x - g * 40;      // 0..39
    int node = blockIdx.x * 8 + g;
    int d = l >> 3;                    // 8 lanes per d
    int start = rowStart[node];
    int end   = rowStart[node + 1];
    float a0 = 0.f, a1 = 0.f, a2 = 0.f, a3 = 0.f, ss = 0.f;
    int k = start;
    for (; k + 7 < end; k += 8) {
        int2 ce[8]; float av[8]; uint2 hv[8];
#pragma unroll
        for (int u = 0; u < 8; ++u) ce[u] = csr[k + u];
#pragma unroll
        for (int u = 0; u < 8; ++u) av[u] = bf2f(es2[(size_t)ce[u].y * DIMS + d]);
#pragma unroll
        for (int u = 0; u < 8; ++u)
            hv[u] = *(const uint2*)(h2 + (size_t)ce[u].x * FEAT + l * 4);
#pragma unroll
        for (int u = 0; u < 8; ++u) {
            float a = av[u];
            ss += a;
            a0 += a * __uint_as_float(hv[u].x << 16);
            a1 += a * __uint_as_float(hv[u].x & 0xffff0000u);
            a2 += a * __uint_as_float(hv[u].y << 16);
            a3 += a * __uint_as_float(hv[u].y & 0xffff0000u);
        }
    }
    for (; k < end; ++k) {
        int2 ce = csr[k];
        float a = bf2f(es2[(size_t)ce.y * DIMS + d]);
        uint2 hv = *(const uint2*)(h2 + (size_t)ce.x * FEAT + l * 4);
        ss += a;
        a0 += a * __uint_as_float(hv.x << 16);
        a1 += a * __uint_as_float(hv.x & 0xffff0000u);
        a2 += a * __uint_as_float(hv.y << 16);
        a3 += a * __uint_as_float(hv.y & 0xffff0000u);
    }
    float inv = 1.f / (ss + 1e-16f);
    union { float f[4]; unsigned long long u[2]; } o;
    o.f[0] = a0 * inv; o.f[1] = a1 * inv; o.f[2] = a2 * inv; o.f[3] = a3 * inv;
    unsigned long long* op = (unsigned long long*)(out + (size_t)node * FEAT + l * 4);
    __builtin_nontemporal_store(o.u[0], op);
    __builtin_nontemporal_store(o.u[1], op + 1);
    if ((l & 7) == 0) ssum[node * DIMS + d] = ss;
}

// ---- alpha = bf16(es) / ssum[row] ----
__global__ void alpha_kernel(const int* __restrict__ ei,
                             const unsigned short* __restrict__ es2,
                             const float* __restrict__ ssum,
                             float* __restrict__ alpha_buf) {
    int idx = blockIdx.x * blockDim.x + threadIdx.x;
    if (idx >= N_EDGES * DIMS) return;
    int e = idx / DIMS;
    int d = idx - e * DIMS;
    int r = ei[e];
    float a = bf2f(es2[idx]) / (ssum[r * DIMS + d] + 1e-16f);
    __builtin_nontemporal_store(a, &alpha_buf[idx]);
}

extern "C" void kernel_launch(void* const* d_in, const int* in_sizes, int n_in,
                              void* d_out, int out_size, void* d_ws, size_t ws_size,
                              hipStream_t stream) {
    const float* x         = (const float*)d_in[0];
    const int*   ei        = (const int*)d_in[1];
    const float* edge_attr = (const float*)d_in[2];
    const float* W         = (const float*)d_in[3];
    const float* att       = (const float*)d_in[4];

    float* out_buf   = (float*)d_out;                       // 8,000,000 f32
    float* alpha_buf = out_buf + (size_t)N_NODES * FEAT;    // 4,000,000 f32
    float* fedge     = alpha_buf + (size_t)N_EDGES * DIMS;  // 1,600,000 f32

    char* wsb = (char*)d_ws;
    __hip_bfloat16* h2 = (__hip_bfloat16*)wsb;              //  0 .. 16,000,000
    float* ai     = (float*)(wsb + 16000000);               // 1,000,000 B
    float* aj     = (float*)(wsb + 17000000);               // 1,000,000 B
    float* ssum   = (float*)(wsb + 18000000);               // 1,000,000 B
    int2* csr     = (int2*)(wsb + 19000000);                // 6,400,000 B
    int* rowStart = (int*)(wsb + 25400000);                 // 200,004 B
    int* ghist    = (int*)(wsb + 25600064);                 // 306,544 B
    int* base2    = (int*)(wsb + 25906624);                 // 306,544 B
    int* btot     = (int*)(wsb + 26213184);                 // 1,564 B
    int* bbase    = (int*)(wsb + 26214784);                 // 1,564 B
    int2* staged  = (int2*)(wsb + 26216384);                // 6,400,000 B (dead after build)
    unsigned short* lofs = (unsigned short*)(wsb + 32616384); // 1,600,000 B (dead after place)
    unsigned short* es2  = (unsigned short*)(wsb + 26216384); // 8,000,000 B (aliases staged+lofs)

    const int B = 256;

    hist_kernel<<<K1_BLOCKS, 1024, 0, stream>>>(ei, fedge, ghist, lofs);
    colsum_kernel<<<NBUCK, 256, 0, stream>>>(ghist, btot);
    bscan2_kernel<<<1, 512, 0, stream>>>(btot, bbase);
    colscan_kernel<<<NBUCK, 256, 0, stream>>>(ghist, bbase, base2);
    place_kernel<<<K1_BLOCKS, 1024, 0, stream>>>(ei, lofs, base2, staged);
    build_kernel<<<NBUCK, 256, 0, stream>>>(staged, btot, bbase, csr, rowStart);
    hfused_kernel<<<(N_NODES * 8 + B - 1) / B, B, 0, stream>>>(x, W, att, h2, ai, aj);
    es_kernel<<<(N_EDGES * DIMS + B - 1) / B, B, 0, stream>>>(ei, edge_attr, ai, aj, att, es2);
    out_kernel<<<N_NODES / 8, 320, 0, stream>>>(h2, es2, csr, rowStart, out_buf, ssum);
    alpha_kernel<<<(N_EDGES * DIMS + B - 1) / B, B, 0, stream>>>(ei, es2, ssum, alpha_buf);
}